// Round 5
// baseline (5425.768 us; speedup 1.0000x reference)
//
#include <hip/hip_runtime.h>
#include <cstdint>
#include <cstddef>

// LSTM decoder B=256,H=1024,T=128. Persistent kernel: 256 blocks x 1024 thr
// (1 block/CU, 16 waves = 4/SIMD). Block owns 8 cols x 4 gates (packed N=32);
// weights hi/lo bf16 in 128KB LDS (XOR-swizzled). 3-pass bf16 MFMA
// (h1@W1 + h2@W1 + h1@W2 ~ fp32), 6 indep acc chains, K-split across wave
// pairs. NO grid barrier, NO fences: producer flags (sc1) + IF-coherent
// (agent-scope relaxed atomic) h loads/stores. out lines XCD-aligned.

#define DI __device__ __forceinline__

typedef __attribute__((ext_vector_type(8))) short short8;
typedef __attribute__((ext_vector_type(4))) float f32x4;
typedef unsigned short u16;
typedef unsigned int   u32;
typedef unsigned long long u64;

static constexpr int H = 1024;
static constexpr int B = 256;
static constexpr int T = 128;

DI u16 f2bf(float f){
  union { float f; u32 u; } v; v.f = f;
  u32 r = v.u + 0x7fffu + ((v.u >> 16) & 1u);
  return (u16)(r >> 16);
}
DI float bf2f(u16 h){
  union { u32 u; float f; } v; v.u = ((u32)h) << 16; return v.f;
}
DI float sigf(float z){ return 1.0f / (1.0f + __expf(-z)); }
DI float tanh_(float z){
  float e = __expf(-2.0f * fabsf(z));
  float t = (1.0f - e) / (1.0f + e);
  return z < 0.0f ? -t : t;
}

struct P {
  const float *x;
  const float *Wxi,*Wxf,*Wxo,*Wxc;
  const float *Whi,*Whf,*Who,*Whc;
  const float *bxi,*bxf,*bxo,*bxc;
  const float *bhi,*bhf,*bho,*bhc;
  float* out;
  char*  hb;     // 2 x 1MB parity buffers: [row][kb][plane][8] bf16
  u32*   flags;  // [2 parity][2 rg][128 bn] u32 step tags (memset 0)
};

// 16B load via two agent-scope relaxed atomic u64 loads (sc1: IF-served,
// bypasses non-coherent L1/L2 -- no fences needed anywhere).
DI short8 ld16a(const char* a){
  union { u64 q[2]; short8 v; } r;
  r.q[0] = __hip_atomic_load((const u64*)a,       __ATOMIC_RELAXED, __HIP_MEMORY_SCOPE_AGENT);
  r.q[1] = __hip_atomic_load((const u64*)(a + 8), __ATOMIC_RELAXED, __HIP_MEMORY_SCOPE_AGENT);
  return r.v;
}

// Wide poll: 32 lanes watch 32 producer flags until all >= need.
DI void wait_flags(const u32* f, u32 need, int lane){
  for(;;){
    u32 v = 0xFFFFFFFFu;
    if (lane < 32)
      v = __hip_atomic_load(f + lane, __ATOMIC_RELAXED, __HIP_MEMORY_SCOPE_AGENT);
    if (__all((int)(v >= need))) break;
    __builtin_amdgcn_s_sleep(2);
  }
}

// Pack the block's 32 packed-N weight rows x K=1024 into LDS (hi plane at 0,
// lo plane at 64KB), XOR-swizzled. Packed row q: tile t=q>>4, qq=q&15,
// gate = t*2 + (qq&1) [t0:(i,f) t1:(o,c)], col = bn*8 + (qq>>1).
DI void pack_w(char* lds, int bn, int tid,
               const float* Wi, const float* Wf, const float* Wo, const float* Wc){
  #pragma unroll
  for (int i = 0; i < 4; ++i){
    int j0 = tid + i * 1024;           // 4096 jobs: (q, 16B k-chunk)
    int q  = j0 >> 7;
    int kc = j0 & 127;
    int qq = q & 15;
    const float* Wg = (q & 16) ? ((qq & 1) ? Wc : Wo) : ((qq & 1) ? Wf : Wi);
    const float* src = Wg + (size_t)(bn * 8 + (qq >> 1)) * 1024 + kc * 8;
    f32x4 v0 = *(const f32x4*)(src);
    f32x4 v1 = *(const f32x4*)(src + 4);
    short8 hi, lo;
    #pragma unroll
    for (int e = 0; e < 4; ++e){
      u16 h0 = f2bf(v0[e]); hi[e]     = (short)h0; lo[e]     = (short)f2bf(v0[e] - bf2f(h0));
      u16 h1 = f2bf(v1[e]); hi[4 + e] = (short)h1; lo[4 + e] = (short)f2bf(v1[e] - bf2f(h1));
    }
    int addr = (q * 2048 + kc * 16) ^ ((q & 7) << 4);
    *(short8*)(lds + addr)         = hi;
    *(short8*)(lds + 65536 + addr) = lo;
  }
}

DI void comp4(const short8* A1, const short8* A2, int kib,
              const char* lds, int lin0, int lin1, int m,
              f32x4& t0a, f32x4& t0b, f32x4& t0c,
              f32x4& t1a, f32x4& t1b, f32x4& t1c){
  #pragma unroll
  for (int q = 0; q < 4; ++q){
    int ki = kib + q;
    int s0 = (lin0 + ki * 64) ^ m;
    int s1 = (lin1 + ki * 64) ^ m;
    short8 b10 = *(const short8*)(lds + s0);
    short8 b20 = *(const short8*)(lds + 65536 + s0);
    short8 b11 = *(const short8*)(lds + s1);
    short8 b21 = *(const short8*)(lds + 65536 + s1);
    t0a = __builtin_amdgcn_mfma_f32_16x16x32_bf16(A1[q], b10, t0a, 0,0,0);
    t1a = __builtin_amdgcn_mfma_f32_16x16x32_bf16(A1[q], b11, t1a, 0,0,0);
    t0b = __builtin_amdgcn_mfma_f32_16x16x32_bf16(A2[q], b10, t0b, 0,0,0);
    t1b = __builtin_amdgcn_mfma_f32_16x16x32_bf16(A2[q], b11, t1b, 0,0,0);
    t0c = __builtin_amdgcn_mfma_f32_16x16x32_bf16(A1[q], b20, t0c, 0,0,0);
    t1c = __builtin_amdgcn_mfma_f32_16x16x32_bf16(A1[q], b21, t1c, 0,0,0);
  }
}

__global__ __launch_bounds__(1024, 4) void lstm_kernel(P p){
  __shared__ char lds[147456];            // 128K weights + 16K combine scratch
  char* scratch = lds + 131072;
  const int tid  = threadIdx.x;
  const int lane = tid & 63;
  const int wv   = tid >> 6;              // 0..15
  const int w8   = wv & 7;                // M-tile
  const int kh   = wv >> 3;               // K-half
  const int l15  = lane & 15;
  const int lhi  = lane >> 4;
  const int l7   = lane & 7;
  const int blk  = blockIdx.x;
  // XCD-aligned mapping: XCD x owns bn 16x..16x+15 (both rgs) -> both
  // writers of every 64B out line share one XCD L2 (no cross-XCD RMW).
  const int xcd  = blk & 7;
  const int s    = blk >> 3;              // 0..31
  const int rg   = s & 1;
  const int bn   = (xcd << 4) | (s >> 1); // 0..127
  const int rowbase = rg * 128 + w8 * 16;
  const int col  = bn * 8 + (l15 >> 1);
  const bool odd = (l15 & 1);
  const int kbase = kh * 512;

  // swizzled-LDS lane constants (B-fragment addressing)
  const int lin0 = l15 * 2048 + lhi * 16 + kbase * 2;
  const int lin1 = (16 + l15) * 2048 + lhi * 16 + kbase * 2;
  const int m    = l7 << 4;

  // ---- phase 1: pack Wx -> LDS, compute xpre (this block's 128 rows)
  pack_w(lds, bn, tid, p.Wxi, p.Wxf, p.Wxo, p.Wxc);
  __syncthreads();

  f32x4 xp0 = {0.f,0.f,0.f,0.f}, xp1 = {0.f,0.f,0.f,0.f};
  {
    f32x4 t0a={0,0,0,0},t0b={0,0,0,0},t0c={0,0,0,0};
    f32x4 t1a={0,0,0,0},t1b={0,0,0,0},t1c={0,0,0,0};
    const float* xr = p.x + (size_t)(rowbase + l15) * 1024 + kbase + lhi * 8;
    #pragma unroll 4
    for (int k0 = 0; k0 < 512; k0 += 32){
      f32x4 v0 = *(const f32x4*)(xr + k0);
      f32x4 v1 = *(const f32x4*)(xr + k0 + 4);
      short8 a1, a2;
      #pragma unroll
      for (int e = 0; e < 4; ++e){
        u16 h0 = f2bf(v0[e]); a1[e]     = (short)h0; a2[e]     = (short)f2bf(v0[e] - bf2f(h0));
        u16 h1 = f2bf(v1[e]); a1[4 + e] = (short)h1; a2[4 + e] = (short)f2bf(v1[e] - bf2f(h1));
      }
      int s0 = (lin0 + k0 * 2) ^ m;
      int s1 = (lin1 + k0 * 2) ^ m;
      short8 b10 = *(const short8*)(lds + s0);
      short8 b20 = *(const short8*)(lds + 65536 + s0);
      short8 b11 = *(const short8*)(lds + s1);
      short8 b21 = *(const short8*)(lds + 65536 + s1);
      t0a = __builtin_amdgcn_mfma_f32_16x16x32_bf16(a1, b10, t0a, 0,0,0);
      t1a = __builtin_amdgcn_mfma_f32_16x16x32_bf16(a1, b11, t1a, 0,0,0);
      t0b = __builtin_amdgcn_mfma_f32_16x16x32_bf16(a2, b10, t0b, 0,0,0);
      t1b = __builtin_amdgcn_mfma_f32_16x16x32_bf16(a2, b11, t1b, 0,0,0);
      t0c = __builtin_amdgcn_mfma_f32_16x16x32_bf16(a1, b20, t0c, 0,0,0);
      t1c = __builtin_amdgcn_mfma_f32_16x16x32_bf16(a1, b21, t1c, 0,0,0);
    }
    xp0 = t0a + t0b + t0c;
    xp1 = t1a + t1b + t1c;
  }
  // combine K-halves through LDS scratch
  if (wv >= 8){
    char* d = scratch + (((wv - 8) * 64 + lane) << 5);
    *(f32x4*)d        = xp0;
    *(f32x4*)(d + 16) = xp1;
  }
  __syncthreads();
  if (wv < 8){
    const char* sc = scratch + ((wv * 64 + lane) << 5);
    xp0 += *(const f32x4*)sc;
    xp1 += *(const f32x4*)(sc + 16);
    float bx0 = odd ? p.bxf[col] : p.bxi[col];
    float bh0 = odd ? p.bhf[col] : p.bhi[col];
    float bx1 = odd ? p.bxc[col] : p.bxo[col];
    float bh1 = odd ? p.bhc[col] : p.bho[col];
    #pragma unroll
    for (int j = 0; j < 4; ++j){ xp0[j] += bx0 + bh0; xp1[j] += bx1 + bh1; }
  }
  __syncthreads();

  // ---- phase 2: pack Wh -> LDS (stays for all 128 steps)
  pack_w(lds, bn, tid, p.Whi, p.Whf, p.Who, p.Whc);
  __syncthreads();

  // ---- recurrent steps
  f32x4 cc = {0.f,0.f,0.f,0.f};
  for (int t = 0; t < T; ++t){
    f32x4 r0 = {0.f,0.f,0.f,0.f}, r1 = {0.f,0.f,0.f,0.f};
    if (t > 0){
      f32x4 t0a={0,0,0,0},t0b={0,0,0,0},t0c={0,0,0,0};
      f32x4 t1a={0,0,0,0},t1b={0,0,0,0},t1c={0,0,0,0};
      const char* aB = p.hb + (((t + 1) & 1) << 20)
                     + (size_t)(rowbase + l15) * 4096 + kbase * 4 + lhi * 32;
      const u32* fb = p.flags + (((t + 1) & 1) << 8) + rg * 128 + kh * 64;
      short8 A1c[4], A2c[4], A1n[4], A2n[4];

      wait_flags(fb, (u32)t, lane);                    // group 0 producers
      #pragma unroll
      for (int i = 0; i < 4; ++i){
        A1c[i] = ld16a(aB + i * 128); A2c[i] = ld16a(aB + i * 128 + 16);
      }
      #pragma unroll
      for (int i = 0; i < 4; ++i){
        A1n[i] = ld16a(aB + (4+i) * 128); A2n[i] = ld16a(aB + (4+i) * 128 + 16);
      }
      comp4(A1c, A2c, 0, lds, lin0, lin1, m, t0a,t0b,t0c,t1a,t1b,t1c);
      wait_flags(fb + 32, (u32)t, lane);               // group 1 producers
      #pragma unroll
      for (int i = 0; i < 4; ++i){
        A1c[i] = ld16a(aB + (8+i) * 128); A2c[i] = ld16a(aB + (8+i) * 128 + 16);
      }
      comp4(A1n, A2n, 4, lds, lin0, lin1, m, t0a,t0b,t0c,t1a,t1b,t1c);
      #pragma unroll
      for (int i = 0; i < 4; ++i){
        A1n[i] = ld16a(aB + (12+i) * 128); A2n[i] = ld16a(aB + (12+i) * 128 + 16);
      }
      comp4(A1c, A2c, 8, lds, lin0, lin1, m, t0a,t0b,t0c,t1a,t1b,t1c);
      comp4(A1n, A2n, 12, lds, lin0, lin1, m, t0a,t0b,t0c,t1a,t1b,t1c);
      r0 = t0a + t0b + t0c;
      r1 = t1a + t1b + t1c;
    }
    // combine K-halves
    if (wv >= 8){
      char* d = scratch + (((wv - 8) * 64 + lane) << 5);
      *(f32x4*)d        = r0;
      *(f32x4*)(d + 16) = r1;
    }
    __syncthreads();
    if (wv < 8){
      const char* sc = scratch + ((wv * 64 + lane) << 5);
      r0 += *(const f32x4*)sc;
      r1 += *(const f32x4*)(sc + 16);
      // elementwise update; tile0 lane pair holds (i,f), tile1 (o,c~)
      char* hout = p.hb + ((t & 1) << 20);
      #pragma unroll
      for (int j = 0; j < 4; ++j){
        float p0 = r0[j] + xp0[j];
        float p1 = r1[j] + xp1[j];
        float q0 = __shfl_xor(p0, 1);
        float q1 = __shfl_xor(p1, 1);
        float iv = odd ? q0 : p0, fv = odd ? p0 : q0;
        float ov = odd ? q1 : p1, gv = odd ? p1 : q1;
        float cn = sigf(fv) * cc[j] + sigf(iv) * tanh_(gv);
        cc[j] = cn;
        float h = sigf(ov) * tanh_(cn);
        int row = rowbase + lhi * 4 + j;
        if (!odd){
          p.out[((size_t)row * T + t) * H + col] = h;
        } else if (t != T - 1){
          u16 h1 = f2bf(h);
          u16 h2 = f2bf(h - bf2f(h1));
          char* d = hout + (size_t)row * 4096 + ((col >> 3) << 5) + ((col & 7) << 1);
          // agent-scope write-through: lands at IF (coherence point)
          __hip_atomic_store((u16*)d,        h1, __ATOMIC_RELAXED, __HIP_MEMORY_SCOPE_AGENT);
          __hip_atomic_store((u16*)(d + 16), h2, __ATOMIC_RELAXED, __HIP_MEMORY_SCOPE_AGENT);
        }
      }
    }
    // publish: h stores drained by syncthreads (vmcnt(0) before s_barrier),
    // then one sc1 flag store -> strictly ordered at the IF.
    __syncthreads();
    if (tid == 0 && t != T - 1)
      __hip_atomic_store(p.flags + ((t & 1) << 8) + rg * 128 + bn, (u32)(t + 1),
                         __ATOMIC_RELAXED, __HIP_MEMORY_SCOPE_AGENT);
  }
}

extern "C" void kernel_launch(void* const* d_in, const int* in_sizes, int n_in,
                              void* d_out, int out_size, void* d_ws, size_t ws_size,
                              hipStream_t stream){
  (void)in_sizes; (void)n_in; (void)out_size; (void)ws_size;
  P prm;
  prm.x   = (const float*)d_in[0];
  prm.Wxi = (const float*)d_in[1];  prm.bxi = (const float*)d_in[2];
  prm.Whi = (const float*)d_in[3];  prm.bhi = (const float*)d_in[4];
  prm.Wxf = (const float*)d_in[5];  prm.bxf = (const float*)d_in[6];
  prm.Whf = (const float*)d_in[7];  prm.bhf = (const float*)d_in[8];
  prm.Wxo = (const float*)d_in[9];  prm.bxo = (const float*)d_in[10];
  prm.Who = (const float*)d_in[11]; prm.bho = (const float*)d_in[12];
  prm.Wxc = (const float*)d_in[13]; prm.bxc = (const float*)d_in[14];
  prm.Whc = (const float*)d_in[15]; prm.bhc = (const float*)d_in[16];
  prm.out = (float*)d_out;
  prm.hb    = (char*)d_ws;
  prm.flags = (u32*)((char*)d_ws + (2u << 20));

  hipMemsetAsync(prm.flags, 0, 4096, stream);
  lstm_kernel<<<256, 1024, 0, stream>>>(prm);
}

// Round 6
// 2932.266 us; speedup vs baseline: 1.8504x; 1.8504x over previous
//
#include <hip/hip_runtime.h>
#include <cstdint>
#include <cstddef>

// LSTM decoder B=256,H=1024,T=128. Persistent kernel: 256 blocks x 1024 thr
// (1 block/CU, 16 waves = 4/SIMD). Block owns 8 cols x 4 gates (packed N=32);
// weights hi/lo bf16 in 128KB LDS (XOR-swizzled). 3-pass bf16 MFMA
// (h1@W1 + h2@W1 + h1@W2 ~ fp32), 6 indep acc chains, K-split across wave
// pairs. Sync: producer flags (write-through stores) + ONE acquire fence
// (L1+L2 inv) per block/step done by wave 0, LDS-notify releases the rest.
// h A-loads are plain cached loads (L2-served); h stores write-through (sc1).

#define DI __device__ __forceinline__

typedef __attribute__((ext_vector_type(8))) short short8;
typedef __attribute__((ext_vector_type(4))) float f32x4;
typedef unsigned short u16;
typedef unsigned int   u32;

static constexpr int H = 1024;
static constexpr int B = 256;
static constexpr int T = 128;

DI u16 f2bf(float f){
  union { float f; u32 u; } v; v.f = f;
  u32 r = v.u + 0x7fffu + ((v.u >> 16) & 1u);
  return (u16)(r >> 16);
}
DI float bf2f(u16 h){
  union { u32 u; float f; } v; v.u = ((u32)h) << 16; return v.f;
}
DI float sigf(float z){ return 1.0f / (1.0f + __expf(-z)); }
DI float tanh_(float z){
  float e = __expf(-2.0f * fabsf(z));
  float t = (1.0f - e) / (1.0f + e);
  return z < 0.0f ? -t : t;
}

struct P {
  const float *x;
  const float *Wxi,*Wxf,*Wxo,*Wxc;
  const float *Whi,*Whf,*Who,*Whc;
  const float *bxi,*bxf,*bxo,*bxc;
  const float *bhi,*bhf,*bho,*bhc;
  float* out;
  char*  hb;     // 2 x 1MB parity buffers: [row][kb][plane][8] bf16
  u32*   flags;  // [2 parity][2 rg][128 bn] u32 step tags (memset 0)
};

// Pack the block's 32 packed-N weight rows x K=1024 into LDS (hi plane at 0,
// lo plane at 64KB), XOR-swizzled. Packed row q: tile t=q>>4, qq=q&15,
// gate = t*2 + (qq&1) [t0:(i,f) t1:(o,c)], col = bn*8 + (qq>>1).
DI void pack_w(char* lds, int bn, int tid,
               const float* Wi, const float* Wf, const float* Wo, const float* Wc){
  #pragma unroll
  for (int i = 0; i < 4; ++i){
    int j0 = tid + i * 1024;           // 4096 jobs: (q, 16B k-chunk)
    int q  = j0 >> 7;
    int kc = j0 & 127;
    int qq = q & 15;
    const float* Wg = (q & 16) ? ((qq & 1) ? Wc : Wo) : ((qq & 1) ? Wf : Wi);
    const float* src = Wg + (size_t)(bn * 8 + (qq >> 1)) * 1024 + kc * 8;
    f32x4 v0 = *(const f32x4*)(src);
    f32x4 v1 = *(const f32x4*)(src + 4);
    short8 hi, lo;
    #pragma unroll
    for (int e = 0; e < 4; ++e){
      u16 h0 = f2bf(v0[e]); hi[e]     = (short)h0; lo[e]     = (short)f2bf(v0[e] - bf2f(h0));
      u16 h1 = f2bf(v1[e]); hi[4 + e] = (short)h1; lo[4 + e] = (short)f2bf(v1[e] - bf2f(h1));
    }
    int addr = (q * 2048 + kc * 16) ^ ((q & 7) << 4);
    *(short8*)(lds + addr)         = hi;
    *(short8*)(lds + 65536 + addr) = lo;
  }
}

DI void comp4(const short8* A1, const short8* A2, int kib,
              const char* lds, int lin0, int lin1, int m,
              f32x4& t0a, f32x4& t0b, f32x4& t0c,
              f32x4& t1a, f32x4& t1b, f32x4& t1c){
  #pragma unroll
  for (int q = 0; q < 4; ++q){
    int ki = kib + q;
    int s0 = (lin0 + ki * 64) ^ m;
    int s1 = (lin1 + ki * 64) ^ m;
    short8 b10 = *(const short8*)(lds + s0);
    short8 b20 = *(const short8*)(lds + 65536 + s0);
    short8 b11 = *(const short8*)(lds + s1);
    short8 b21 = *(const short8*)(lds + 65536 + s1);
    t0a = __builtin_amdgcn_mfma_f32_16x16x32_bf16(A1[q], b10, t0a, 0,0,0);
    t1a = __builtin_amdgcn_mfma_f32_16x16x32_bf16(A1[q], b11, t1a, 0,0,0);
    t0b = __builtin_amdgcn_mfma_f32_16x16x32_bf16(A2[q], b10, t0b, 0,0,0);
    t1b = __builtin_amdgcn_mfma_f32_16x16x32_bf16(A2[q], b11, t1b, 0,0,0);
    t0c = __builtin_amdgcn_mfma_f32_16x16x32_bf16(A1[q], b20, t0c, 0,0,0);
    t1c = __builtin_amdgcn_mfma_f32_16x16x32_bf16(A1[q], b21, t1c, 0,0,0);
  }
}

__global__ __launch_bounds__(1024, 4) void lstm_kernel(P p){
  __shared__ char lds[147584];     // 128K weights + 16K combine scratch + notify
  char* scratch = lds + 131072;
  int*  nfy     = (int*)(lds + 147456);   // [0]=stage0 ready, [1]=stage1 ready
  const int tid  = threadIdx.x;
  const int lane = tid & 63;
  const int wv   = tid >> 6;              // 0..15
  const int w8   = wv & 7;                // M-tile
  const int kh   = wv >> 3;               // K-half
  const int l15  = lane & 15;
  const int lhi  = lane >> 4;
  const int l7   = lane & 7;
  const int blk  = blockIdx.x;
  // XCD-aligned mapping: XCD x owns bn 16x..16x+15 (both rgs) -> both
  // writers of every 64B out line share one XCD L2.
  const int xcd  = blk & 7;
  const int s    = blk >> 3;              // 0..31
  const int rg   = s & 1;
  const int bn   = (xcd << 4) | (s >> 1); // 0..127
  const int rowbase = rg * 128 + w8 * 16;
  const int col  = bn * 8 + (l15 >> 1);
  const bool odd = (l15 & 1);
  const int kbase = kh * 512;

  // swizzled-LDS lane constants (B-fragment addressing)
  const int lin0 = l15 * 2048 + lhi * 16 + kbase * 2;
  const int lin1 = (16 + l15) * 2048 + lhi * 16 + kbase * 2;
  const int m    = l7 << 4;

  if (tid < 2) nfy[tid] = 0;

  // ---- phase 1: pack Wx -> LDS, compute xpre (this block's 128 rows)
  pack_w(lds, bn, tid, p.Wxi, p.Wxf, p.Wxo, p.Wxc);
  __syncthreads();

  f32x4 xp0 = {0.f,0.f,0.f,0.f}, xp1 = {0.f,0.f,0.f,0.f};
  {
    f32x4 t0a={0,0,0,0},t0b={0,0,0,0},t0c={0,0,0,0};
    f32x4 t1a={0,0,0,0},t1b={0,0,0,0},t1c={0,0,0,0};
    const float* xr = p.x + (size_t)(rowbase + l15) * 1024 + kbase + lhi * 8;
    #pragma unroll 4
    for (int k0 = 0; k0 < 512; k0 += 32){
      f32x4 v0 = *(const f32x4*)(xr + k0);
      f32x4 v1 = *(const f32x4*)(xr + k0 + 4);
      short8 a1, a2;
      #pragma unroll
      for (int e = 0; e < 4; ++e){
        u16 h0 = f2bf(v0[e]); a1[e]     = (short)h0; a2[e]     = (short)f2bf(v0[e] - bf2f(h0));
        u16 h1 = f2bf(v1[e]); a1[4 + e] = (short)h1; a2[4 + e] = (short)f2bf(v1[e] - bf2f(h1));
      }
      int s0 = (lin0 + k0 * 2) ^ m;
      int s1 = (lin1 + k0 * 2) ^ m;
      short8 b10 = *(const short8*)(lds + s0);
      short8 b20 = *(const short8*)(lds + 65536 + s0);
      short8 b11 = *(const short8*)(lds + s1);
      short8 b21 = *(const short8*)(lds + 65536 + s1);
      t0a = __builtin_amdgcn_mfma_f32_16x16x32_bf16(a1, b10, t0a, 0,0,0);
      t1a = __builtin_amdgcn_mfma_f32_16x16x32_bf16(a1, b11, t1a, 0,0,0);
      t0b = __builtin_amdgcn_mfma_f32_16x16x32_bf16(a2, b10, t0b, 0,0,0);
      t1b = __builtin_amdgcn_mfma_f32_16x16x32_bf16(a2, b11, t1b, 0,0,0);
      t0c = __builtin_amdgcn_mfma_f32_16x16x32_bf16(a1, b20, t0c, 0,0,0);
      t1c = __builtin_amdgcn_mfma_f32_16x16x32_bf16(a1, b21, t1c, 0,0,0);
    }
    xp0 = t0a + t0b + t0c;
    xp1 = t1a + t1b + t1c;
  }
  if (wv >= 8){
    char* d = scratch + (((wv - 8) * 64 + lane) << 5);
    *(f32x4*)d        = xp0;
    *(f32x4*)(d + 16) = xp1;
  }
  __syncthreads();
  if (wv < 8){
    const char* sc = scratch + ((wv * 64 + lane) << 5);
    xp0 += *(const f32x4*)sc;
    xp1 += *(const f32x4*)(sc + 16);
    float bx0 = odd ? p.bxf[col] : p.bxi[col];
    float bh0 = odd ? p.bhf[col] : p.bhi[col];
    float bx1 = odd ? p.bxc[col] : p.bxo[col];
    float bh1 = odd ? p.bhc[col] : p.bho[col];
    #pragma unroll
    for (int j = 0; j < 4; ++j){ xp0[j] += bx0 + bh0; xp1[j] += bx1 + bh1; }
  }
  __syncthreads();

  // ---- phase 2: pack Wh -> LDS (stays for all 128 steps)
  pack_w(lds, bn, tid, p.Whi, p.Whf, p.Who, p.Whc);
  __syncthreads();

  // ---- recurrent steps
  f32x4 cc = {0.f,0.f,0.f,0.f};
  for (int t = 0; t < T; ++t){
    f32x4 r0 = {0.f,0.f,0.f,0.f}, r1 = {0.f,0.f,0.f,0.f};
    if (t > 0){
      f32x4 t0a={0,0,0,0},t0b={0,0,0,0},t0c={0,0,0,0};
      f32x4 t1a={0,0,0,0},t1b={0,0,0,0},t1c={0,0,0,0};
      const char* aB = p.hb + (((t + 1) & 1) << 20)
                     + (size_t)(rowbase + l15) * 4096 + kbase * 4 + lhi * 32;
      // flags: [parity][rg][bn']; lane-mapped so stage0 = bn' {0..31, 64..95}
      const u32* fl = p.flags + (((t + 1) & 1) << 8) + rg * 128
                    + ((lane < 32) ? lane : (lane + 32));

      if (wv == 0){
        // stage-0 producers (both kh groups)
        for(;;){
          u32 v = __hip_atomic_load(fl, __ATOMIC_RELAXED, __HIP_MEMORY_SCOPE_AGENT);
          if (__all((int)(v >= (u32)t))) break;
          __builtin_amdgcn_s_sleep(4);
        }
        // single inv per block/step: drops every stale h line in L1+L2.
        __builtin_amdgcn_fence(__ATOMIC_ACQUIRE, "agent");
        asm volatile("s_waitcnt vmcnt(0)" ::: "memory");
        __hip_atomic_store(nfy, t, __ATOMIC_RELEASE, __HIP_MEMORY_SCOPE_WORKGROUP);
        // stage-1 producers (lines are inv'd & untouched until after this)
        for(;;){
          u32 v = __hip_atomic_load(fl + 32, __ATOMIC_RELAXED, __HIP_MEMORY_SCOPE_AGENT);
          if (__all((int)(v >= (u32)t))) break;
          __builtin_amdgcn_s_sleep(4);
        }
        __hip_atomic_store(nfy + 1, t, __ATOMIC_RELEASE, __HIP_MEMORY_SCOPE_WORKGROUP);
      } else {
        while (__hip_atomic_load(nfy, __ATOMIC_ACQUIRE, __HIP_MEMORY_SCOPE_WORKGROUP) < t)
          __builtin_amdgcn_s_sleep(1);
      }

      short8 A1c[4], A2c[4], A1n[4], A2n[4];
      #pragma unroll
      for (int i = 0; i < 4; ++i){
        A1c[i] = *(const short8*)(aB + i * 128);
        A2c[i] = *(const short8*)(aB + i * 128 + 16);
      }
      #pragma unroll
      for (int i = 0; i < 4; ++i){
        A1n[i] = *(const short8*)(aB + (4 + i) * 128);
        A2n[i] = *(const short8*)(aB + (4 + i) * 128 + 16);
      }
      comp4(A1c, A2c, 0, lds, lin0, lin1, m, t0a,t0b,t0c,t1a,t1b,t1c);
      if (wv != 0)
        while (__hip_atomic_load(nfy + 1, __ATOMIC_ACQUIRE, __HIP_MEMORY_SCOPE_WORKGROUP) < t)
          __builtin_amdgcn_s_sleep(1);
      #pragma unroll
      for (int i = 0; i < 4; ++i){
        A1c[i] = *(const short8*)(aB + (8 + i) * 128);
        A2c[i] = *(const short8*)(aB + (8 + i) * 128 + 16);
      }
      comp4(A1n, A2n, 4, lds, lin0, lin1, m, t0a,t0b,t0c,t1a,t1b,t1c);
      #pragma unroll
      for (int i = 0; i < 4; ++i){
        A1n[i] = *(const short8*)(aB + (12 + i) * 128);
        A2n[i] = *(const short8*)(aB + (12 + i) * 128 + 16);
      }
      comp4(A1c, A2c, 8, lds, lin0, lin1, m, t0a,t0b,t0c,t1a,t1b,t1c);
      comp4(A1n, A2n, 12, lds, lin0, lin1, m, t0a,t0b,t0c,t1a,t1b,t1c);
      r0 = t0a + t0b + t0c;
      r1 = t1a + t1b + t1c;
    }
    // combine K-halves
    if (wv >= 8){
      char* d = scratch + (((wv - 8) * 64 + lane) << 5);
      *(f32x4*)d        = r0;
      *(f32x4*)(d + 16) = r1;
    }
    __syncthreads();
    if (wv < 8){
      const char* sc = scratch + ((wv * 64 + lane) << 5);
      r0 += *(const f32x4*)sc;
      r1 += *(const f32x4*)(sc + 16);
      // elementwise update; tile0 lane pair holds (i,f), tile1 (o,c~)
      char* hout = p.hb + ((t & 1) << 20);
      #pragma unroll
      for (int j = 0; j < 4; ++j){
        float p0 = r0[j] + xp0[j];
        float p1 = r1[j] + xp1[j];
        float q0 = __shfl_xor(p0, 1);
        float q1 = __shfl_xor(p1, 1);
        float iv = odd ? q0 : p0, fv = odd ? p0 : q0;
        float ov = odd ? q1 : p1, gv = odd ? p1 : q1;
        float cn = sigf(fv) * cc[j] + sigf(iv) * tanh_(gv);
        cc[j] = cn;
        float h = sigf(ov) * tanh_(cn);
        int row = rowbase + lhi * 4 + j;
        if (!odd){
          p.out[((size_t)row * T + t) * H + col] = h;
        } else if (t != T - 1){
          u16 h1 = f2bf(h);
          u16 h2 = f2bf(h - bf2f(h1));
          char* d = hout + (size_t)row * 4096 + ((col >> 3) << 5) + ((col & 7) << 1);
          // agent-scope write-through: lands at IF (coherence point)
          __hip_atomic_store((u16*)d,        h1, __ATOMIC_RELAXED, __HIP_MEMORY_SCOPE_AGENT);
          __hip_atomic_store((u16*)(d + 16), h2, __ATOMIC_RELAXED, __HIP_MEMORY_SCOPE_AGENT);
        }
      }
    }
    // publish: syncthreads drains all waves' h stores (vmcnt0 before barrier),
    // then one write-through flag store per block.
    __syncthreads();
    if (tid == 0 && t != T - 1)
      __hip_atomic_store(p.flags + ((t & 1) << 8) + rg * 128 + bn, (u32)(t + 1),
                         __ATOMIC_RELAXED, __HIP_MEMORY_SCOPE_AGENT);
  }
}

extern "C" void kernel_launch(void* const* d_in, const int* in_sizes, int n_in,
                              void* d_out, int out_size, void* d_ws, size_t ws_size,
                              hipStream_t stream){
  (void)in_sizes; (void)n_in; (void)out_size; (void)ws_size;
  P prm;
  prm.x   = (const float*)d_in[0];
  prm.Wxi = (const float*)d_in[1];  prm.bxi = (const float*)d_in[2];
  prm.Whi = (const float*)d_in[3];  prm.bhi = (const float*)d_in[4];
  prm.Wxf = (const float*)d_in[5];  prm.bxf = (const float*)d_in[6];
  prm.Whf = (const float*)d_in[7];  prm.bhf = (const float*)d_in[8];
  prm.Wxo = (const float*)d_in[9];  prm.bxo = (const float*)d_in[10];
  prm.Who = (const float*)d_in[11]; prm.bho = (const float*)d_in[12];
  prm.Wxc = (const float*)d_in[13]; prm.bxc = (const float*)d_in[14];
  prm.Whc = (const float*)d_in[15]; prm.bhc = (const float*)d_in[16];
  prm.out = (float*)d_out;
  prm.hb    = (char*)d_ws;
  prm.flags = (u32*)((char*)d_ws + (2u << 20));

  hipMemsetAsync(prm.flags, 0, 4096, stream);
  lstm_kernel<<<256, 1024, 0, stream>>>(prm);
}

// Round 7
// 1931.926 us; speedup vs baseline: 2.8085x; 1.5178x over previous
//
#include <hip/hip_runtime.h>
#include <cstdint>
#include <cstddef>

// LSTM decoder B=256,H=1024,T=128. Persistent kernel: 256 blocks x 1024 thr
// (1 block/CU, 16 waves = 4/SIMD). Block owns 8 cols x 4 gates (packed N=32);
// weights hi/lo bf16 in 128KB LDS (XOR-swizzled). h is SINGLE-plane bf16;
// 2-pass MFMA (h@W1 + h@W2), 4 indep acc chains, K-split across wave pairs
// (combine via conflict-free 16B-stride LDS scratch). h writeout staged in
// LDS then 16B/row write-through stores. Sync: producer flags + one acquire
// fence per block/step by wave 0, LDS-notify releases other waves.

#define DI __device__ __forceinline__

typedef __attribute__((ext_vector_type(8))) short short8;
typedef __attribute__((ext_vector_type(4))) float f32x4;
typedef unsigned short u16;
typedef unsigned int   u32;
typedef unsigned long long u64;

static constexpr int H = 1024;
static constexpr int B = 256;
static constexpr int T = 128;

// LDS map
static constexpr int LDS_SC0 = 131072;   // 8KB combine plane0
static constexpr int LDS_SC1 = 139264;   // 8KB combine plane1
static constexpr int LDS_HST = 147456;   // 2KB h staging (128 rows x 16B)
static constexpr int LDS_NFY = 149504;   // notify words

DI u16 f2bf(float f){
  union { float f; u32 u; } v; v.f = f;
  u32 r = v.u + 0x7fffu + ((v.u >> 16) & 1u);
  return (u16)(r >> 16);
}
DI float bf2f(u16 h){
  union { u32 u; float f; } v; v.u = ((u32)h) << 16; return v.f;
}
DI float sigf(float z){ return 1.0f / (1.0f + __expf(-z)); }
DI float tanh_(float z){
  float e = __expf(-2.0f * fabsf(z));
  float t = (1.0f - e) / (1.0f + e);
  return z < 0.0f ? -t : t;
}

struct P {
  const float *x;
  const float *Wxi,*Wxf,*Wxo,*Wxc;
  const float *Whi,*Whf,*Who,*Whc;
  const float *bxi,*bxf,*bxo,*bxc;
  const float *bhi,*bhf,*bho,*bhc;
  float* out;
  char*  hb;     // 2 x 512KB parity buffers: [row][1024] bf16
  u32*   flags;  // [2 parity][2 rg][128 bn] u32 step tags (memset 0)
};

// Pack the block's 32 packed-N weight rows x K=1024 into LDS (hi plane at 0,
// lo plane at 64KB), XOR-swizzled. Packed row q: tile t=q>>4, qq=q&15,
// gate = t*2 + (qq&1) [t0:(i,f) t1:(o,c)], col = bn*8 + (qq>>1).
DI void pack_w(char* lds, int bn, int tid,
               const float* Wi, const float* Wf, const float* Wo, const float* Wc){
  #pragma unroll
  for (int i = 0; i < 4; ++i){
    int j0 = tid + i * 1024;           // 4096 jobs: (q, 16B k-chunk)
    int q  = j0 >> 7;
    int kc = j0 & 127;
    int qq = q & 15;
    const float* Wg = (q & 16) ? ((qq & 1) ? Wc : Wo) : ((qq & 1) ? Wf : Wi);
    const float* src = Wg + (size_t)(bn * 8 + (qq >> 1)) * 1024 + kc * 8;
    f32x4 v0 = *(const f32x4*)(src);
    f32x4 v1 = *(const f32x4*)(src + 4);
    short8 hi, lo;
    #pragma unroll
    for (int e = 0; e < 4; ++e){
      u16 h0 = f2bf(v0[e]); hi[e]     = (short)h0; lo[e]     = (short)f2bf(v0[e] - bf2f(h0));
      u16 h1 = f2bf(v1[e]); hi[4 + e] = (short)h1; lo[4 + e] = (short)f2bf(v1[e] - bf2f(h1));
    }
    int addr = (q * 2048 + kc * 16) ^ ((q & 7) << 4);
    *(short8*)(lds + addr)         = hi;
    *(short8*)(lds + 65536 + addr) = lo;
  }
}

// 2-pass: A @ W_hi + A @ W_lo for both N-tiles; 4 independent chains.
DI void comp4s(const short8* A, int kib, const char* lds, int lin0, int lin1, int m,
               f32x4& t0a, f32x4& t0c, f32x4& t1a, f32x4& t1c){
  #pragma unroll
  for (int q = 0; q < 4; ++q){
    int ki = kib + q;
    int s0 = (lin0 + ki * 64) ^ m;
    int s1 = (lin1 + ki * 64) ^ m;
    short8 b10 = *(const short8*)(lds + s0);
    short8 b20 = *(const short8*)(lds + 65536 + s0);
    short8 b11 = *(const short8*)(lds + s1);
    short8 b21 = *(const short8*)(lds + 65536 + s1);
    t0a = __builtin_amdgcn_mfma_f32_16x16x32_bf16(A[q], b10, t0a, 0,0,0);
    t1a = __builtin_amdgcn_mfma_f32_16x16x32_bf16(A[q], b11, t1a, 0,0,0);
    t0c = __builtin_amdgcn_mfma_f32_16x16x32_bf16(A[q], b20, t0c, 0,0,0);
    t1c = __builtin_amdgcn_mfma_f32_16x16x32_bf16(A[q], b21, t1c, 0,0,0);
  }
}

__global__ __launch_bounds__(1024, 4) void lstm_kernel(P p){
  __shared__ char lds[149632];
  u16* hst = (u16*)(lds + LDS_HST);
  int* nfy = (int*)(lds + LDS_NFY);       // [0]=stage0 ready, [1]=stage1 ready
  const int tid  = threadIdx.x;
  const int lane = tid & 63;
  const int wv   = tid >> 6;              // 0..15
  const int w8   = wv & 7;                // M-tile
  const int kh   = wv >> 3;               // K-half
  const int l15  = lane & 15;
  const int lhi  = lane >> 4;
  const int l7   = lane & 7;
  const int blk  = blockIdx.x;
  // XCD-aligned mapping: XCD x owns bn 16x..16x+15 (both rgs).
  const int xcd  = blk & 7;
  const int s    = blk >> 3;              // 0..31
  const int rg   = s & 1;
  const int bn   = (xcd << 4) | (s >> 1); // 0..127
  const int rowbase = rg * 128 + w8 * 16;
  const int col  = bn * 8 + (l15 >> 1);
  const bool odd = (l15 & 1);
  const int kbase = kh * 512;

  // swizzled-LDS lane constants (B-fragment addressing)
  const int lin0 = l15 * 2048 + lhi * 16 + kbase * 2;
  const int lin1 = (16 + l15) * 2048 + lhi * 16 + kbase * 2;
  const int m    = l7 << 4;

  if (tid < 2) nfy[tid] = 0;

  // ---- phase 1: pack Wx -> LDS, compute xpre (this block's 128 rows).
  // x is fp32: full hi/lo 3-pass here (one-time, exactness matters).
  pack_w(lds, bn, tid, p.Wxi, p.Wxf, p.Wxo, p.Wxc);
  __syncthreads();

  f32x4 xp0 = {0.f,0.f,0.f,0.f}, xp1 = {0.f,0.f,0.f,0.f};
  {
    f32x4 t0a={0,0,0,0},t0b={0,0,0,0},t0c={0,0,0,0};
    f32x4 t1a={0,0,0,0},t1b={0,0,0,0},t1c={0,0,0,0};
    const float* xr = p.x + (size_t)(rowbase + l15) * 1024 + kbase + lhi * 8;
    #pragma unroll 4
    for (int k0 = 0; k0 < 512; k0 += 32){
      f32x4 v0 = *(const f32x4*)(xr + k0);
      f32x4 v1 = *(const f32x4*)(xr + k0 + 4);
      short8 a1, a2;
      #pragma unroll
      for (int e = 0; e < 4; ++e){
        u16 h0 = f2bf(v0[e]); a1[e]     = (short)h0; a2[e]     = (short)f2bf(v0[e] - bf2f(h0));
        u16 h1 = f2bf(v1[e]); a1[4 + e] = (short)h1; a2[4 + e] = (short)f2bf(v1[e] - bf2f(h1));
      }
      int s0 = (lin0 + k0 * 2) ^ m;
      int s1 = (lin1 + k0 * 2) ^ m;
      short8 b10 = *(const short8*)(lds + s0);
      short8 b20 = *(const short8*)(lds + 65536 + s0);
      short8 b11 = *(const short8*)(lds + s1);
      short8 b21 = *(const short8*)(lds + 65536 + s1);
      t0a = __builtin_amdgcn_mfma_f32_16x16x32_bf16(a1, b10, t0a, 0,0,0);
      t1a = __builtin_amdgcn_mfma_f32_16x16x32_bf16(a1, b11, t1a, 0,0,0);
      t0b = __builtin_amdgcn_mfma_f32_16x16x32_bf16(a2, b10, t0b, 0,0,0);
      t1b = __builtin_amdgcn_mfma_f32_16x16x32_bf16(a2, b11, t1b, 0,0,0);
      t0c = __builtin_amdgcn_mfma_f32_16x16x32_bf16(a1, b20, t0c, 0,0,0);
      t1c = __builtin_amdgcn_mfma_f32_16x16x32_bf16(a1, b21, t1c, 0,0,0);
    }
    xp0 = t0a + t0b + t0c;
    xp1 = t1a + t1b + t1c;
  }
  if (wv >= 8){
    int idx = ((wv - 8) * 64 + lane) * 16;
    *(f32x4*)(lds + LDS_SC0 + idx) = xp0;
    *(f32x4*)(lds + LDS_SC1 + idx) = xp1;
  }
  __syncthreads();
  if (wv < 8){
    int idx = (wv * 64 + lane) * 16;
    xp0 += *(const f32x4*)(lds + LDS_SC0 + idx);
    xp1 += *(const f32x4*)(lds + LDS_SC1 + idx);
    float bx0 = odd ? p.bxf[col] : p.bxi[col];
    float bh0 = odd ? p.bhf[col] : p.bhi[col];
    float bx1 = odd ? p.bxc[col] : p.bxo[col];
    float bh1 = odd ? p.bhc[col] : p.bho[col];
    #pragma unroll
    for (int j = 0; j < 4; ++j){ xp0[j] += bx0 + bh0; xp1[j] += bx1 + bh1; }
  }
  __syncthreads();

  // ---- phase 2: pack Wh -> LDS (stays for all 128 steps)
  pack_w(lds, bn, tid, p.Whi, p.Whf, p.Who, p.Whc);
  __syncthreads();

  // ---- recurrent steps
  f32x4 cc = {0.f,0.f,0.f,0.f};
  for (int t = 0; t < T; ++t){
    f32x4 r0 = {0.f,0.f,0.f,0.f}, r1 = {0.f,0.f,0.f,0.f};
    if (t > 0){
      f32x4 t0a={0,0,0,0},t0c={0,0,0,0},t1a={0,0,0,0},t1c={0,0,0,0};
      const char* aB = p.hb + ((size_t)((t + 1) & 1) << 19)
                     + (size_t)(rowbase + l15) * 2048 + kbase * 2 + lhi * 16;
      // flags: [parity][rg][bn]; stage0 = bn {0..31, 64..95}
      const u32* fl = p.flags + (((t + 1) & 1) << 8) + rg * 128
                    + ((lane < 32) ? lane : (lane + 32));

      if (wv == 0){
        for(;;){
          u32 v = __hip_atomic_load(fl, __ATOMIC_RELAXED, __HIP_MEMORY_SCOPE_AGENT);
          if (__all((int)(v >= (u32)t))) break;
          __builtin_amdgcn_s_sleep(4);
        }
        // single inv per block/step: drops stale h lines from this CU's L1
        // and the XCD L2.
        __builtin_amdgcn_fence(__ATOMIC_ACQUIRE, "agent");
        asm volatile("s_waitcnt vmcnt(0)" ::: "memory");
        __hip_atomic_store(nfy, t, __ATOMIC_RELEASE, __HIP_MEMORY_SCOPE_WORKGROUP);
        for(;;){
          u32 v = __hip_atomic_load(fl + 32, __ATOMIC_RELAXED, __HIP_MEMORY_SCOPE_AGENT);
          if (__all((int)(v >= (u32)t))) break;
          __builtin_amdgcn_s_sleep(4);
        }
        __hip_atomic_store(nfy + 1, t, __ATOMIC_RELEASE, __HIP_MEMORY_SCOPE_WORKGROUP);
      } else {
        while (__hip_atomic_load(nfy, __ATOMIC_ACQUIRE, __HIP_MEMORY_SCOPE_WORKGROUP) < t)
          __builtin_amdgcn_s_sleep(1);
      }

      short8 Aa[4], Ab[4];
      #pragma unroll
      for (int i = 0; i < 4; ++i) Aa[i] = *(const short8*)(aB + i * 64);
      #pragma unroll
      for (int i = 0; i < 4; ++i) Ab[i] = *(const short8*)(aB + (4 + i) * 64);
      comp4s(Aa, 0, lds, lin0, lin1, m, t0a, t0c, t1a, t1c);
      if (wv != 0)
        while (__hip_atomic_load(nfy + 1, __ATOMIC_ACQUIRE, __HIP_MEMORY_SCOPE_WORKGROUP) < t)
          __builtin_amdgcn_s_sleep(1);
      #pragma unroll
      for (int i = 0; i < 4; ++i) Aa[i] = *(const short8*)(aB + (8 + i) * 64);
      comp4s(Ab, 4, lds, lin0, lin1, m, t0a, t0c, t1a, t1c);
      #pragma unroll
      for (int i = 0; i < 4; ++i) Ab[i] = *(const short8*)(aB + (12 + i) * 64);
      comp4s(Aa, 8, lds, lin0, lin1, m, t0a, t0c, t1a, t1c);
      comp4s(Ab, 12, lds, lin0, lin1, m, t0a, t0c, t1a, t1c);
      r0 = t0a + t0c;
      r1 = t1a + t1c;
    }
    // combine K-halves (conflict-free 16B-stride planes)
    if (wv >= 8){
      int idx = ((wv - 8) * 64 + lane) * 16;
      *(f32x4*)(lds + LDS_SC0 + idx) = r0;
      *(f32x4*)(lds + LDS_SC1 + idx) = r1;
    }
    __syncthreads();
    if (wv < 8){
      int idx = (wv * 64 + lane) * 16;
      r0 += *(const f32x4*)(lds + LDS_SC0 + idx);
      r1 += *(const f32x4*)(lds + LDS_SC1 + idx);
      // elementwise update; tile0 lane pair holds (i,f), tile1 (o,c~)
      #pragma unroll
      for (int j = 0; j < 4; ++j){
        float p0 = r0[j] + xp0[j];
        float p1 = r1[j] + xp1[j];
        float q0 = __shfl_xor(p0, 1);
        float q1 = __shfl_xor(p1, 1);
        float iv = odd ? q0 : p0, fv = odd ? p0 : q0;
        float ov = odd ? q1 : p1, gv = odd ? p1 : q1;
        float cn = sigf(fv) * cc[j] + sigf(iv) * tanh_(gv);
        cc[j] = cn;
        float h = sigf(ov) * tanh_(cn);
        int rowL = w8 * 16 + lhi * 4 + j;    // block-local row 0..127
        if (!odd)
          p.out[((size_t)(rg * 128 + rowL) * T + t) * H + col] = h;
        else
          hst[rowL * 8 + (l15 >> 1)] = f2bf(h);   // stage h in LDS
      }
    }
    // writeout: 128 full 16B row-chunks, write-through to IF; then flag.
    __syncthreads();
    if (t != T - 1){
      if (wv < 2){
        int rowL = (wv << 6) | lane;
        const u64* sp = (const u64*)(lds + LDS_HST + rowL * 16);
        char* dst = p.hb + ((size_t)(t & 1) << 19)
                  + (size_t)(rg * 128 + rowL) * 2048 + bn * 16;
        __hip_atomic_store((u64*)dst,       sp[0], __ATOMIC_RELAXED, __HIP_MEMORY_SCOPE_AGENT);
        __hip_atomic_store((u64*)(dst + 8), sp[1], __ATOMIC_RELAXED, __HIP_MEMORY_SCOPE_AGENT);
      }
      __syncthreads();   // drains the writeout waves' vmcnt
      if (tid == 0)
        __hip_atomic_store(p.flags + ((t & 1) << 8) + rg * 128 + bn, (u32)(t + 1),
                           __ATOMIC_RELAXED, __HIP_MEMORY_SCOPE_AGENT);
    }
  }
}

extern "C" void kernel_launch(void* const* d_in, const int* in_sizes, int n_in,
                              void* d_out, int out_size, void* d_ws, size_t ws_size,
                              hipStream_t stream){
  (void)in_sizes; (void)n_in; (void)out_size; (void)ws_size;
  P prm;
  prm.x   = (const float*)d_in[0];
  prm.Wxi = (const float*)d_in[1];  prm.bxi = (const float*)d_in[2];
  prm.Whi = (const float*)d_in[3];  prm.bhi = (const float*)d_in[4];
  prm.Wxf = (const float*)d_in[5];  prm.bxf = (const float*)d_in[6];
  prm.Whf = (const float*)d_in[7];  prm.bhf = (const float*)d_in[8];
  prm.Wxo = (const float*)d_in[9];  prm.bxo = (const float*)d_in[10];
  prm.Who = (const float*)d_in[11]; prm.bho = (const float*)d_in[12];
  prm.Wxc = (const float*)d_in[13]; prm.bxc = (const float*)d_in[14];
  prm.Whc = (const float*)d_in[15]; prm.bhc = (const float*)d_in[16];
  prm.out = (float*)d_out;
  prm.hb    = (char*)d_ws;
  prm.flags = (u32*)((char*)d_ws + (2u << 20));

  hipMemsetAsync(prm.flags, 0, 4096, stream);
  lstm_kernel<<<256, 1024, 0, stream>>>(prm);
}